// Round 1
// baseline (159.604 us; speedup 1.0000x reference)
//
#include <hip/hip_runtime.h>
#include <math.h>

// EnhancedFinancialGAT — analytical collapse.
//
// All N=2000 graph nodes start with identical features (broadcast of h_i).
// A GAT layer on identical node features outputs, at every node,
//   out[n] = (sum of per-dst softmax alphas) * (W g_row) = W g_row  (to ~1e-16,
// since softmax weights sum to denom/(denom+1e-16) and denom >= 1 thanks to the
// self-loop guaranteeing every dst has at least one incoming edge with
// exp(logit-max)=1). relu(out + b) is again identical across nodes, so by
// induction all 3 GAT layers reduce to dense 256->256 relu layers and the
// edge structure / attention params are numerically irrelevant at fp32.
//
// Remaining model per batch item (B=64):
//   h   = relu(W_in x + b_in)                      [64 -> 256]
//   g   = relu(gat_W[l] g + gat_b[l]), l=0..2      [256 -> 256] x3
//   f   = relu(W_fuse [g ; emb[ci]] + b_fuse)      [320 -> 256]
//   p   = relu(W_p1 f); p = relu(W_p2 p); price = W_p3 p + b_p3
//   d   = relu(W_d1 f); d = relu(W_d2 d); dir   = sigmoid(W_d3 d + b_d3)
// Output: d_out[0..63] = price, d_out[64..127] = direction  (fp32).
//
// One block per item, 256 threads, activations in LDS. ~42 MFLOP total.

#define HIDDEN 256
#define IN_DIM 64
#define EMB_DIM 64
#define FUSE_IN 320
#define B_ITEMS 64

__device__ __forceinline__ float dot_row(const float* __restrict__ W,
                                         const float* __restrict__ in, int K4) {
    // W must be 16B aligned (all row strides here are multiples of 4 floats).
    const float4* __restrict__ W4 = reinterpret_cast<const float4*>(W);
    float acc = 0.f;
#pragma unroll 4
    for (int k = 0; k < K4; ++k) {
        float4 w = W4[k];
        acc = fmaf(w.x, in[4 * k + 0], acc);
        acc = fmaf(w.y, in[4 * k + 1], acc);
        acc = fmaf(w.z, in[4 * k + 2], acc);
        acc = fmaf(w.w, in[4 * k + 3], acc);
    }
    return acc;
}

extern "C" __global__ __launch_bounds__(256) void fin_gat_collapsed(
    const float* __restrict__ x,        // [64,64]
    const int* __restrict__ cidx,       // [64]
    const float* __restrict__ W_in,     // [256,64]
    const float* __restrict__ b_in,     // [256]
    const float* __restrict__ gat_W,    // [3,256,256]
    const float* __restrict__ gat_b,    // [3,256]
    const float* __restrict__ emb,      // [2000,64]
    const float* __restrict__ W_fuse,   // [256,320]
    const float* __restrict__ b_fuse,   // [256]
    const float* __restrict__ W_p1, const float* __restrict__ b_p1,  // [128,256],[128]
    const float* __restrict__ W_p2, const float* __restrict__ b_p2,  // [64,128],[64]
    const float* __restrict__ W_p3, const float* __restrict__ b_p3,  // [1,64],[1]
    const float* __restrict__ W_d1, const float* __restrict__ b_d1,
    const float* __restrict__ W_d2, const float* __restrict__ b_d2,
    const float* __restrict__ W_d3, const float* __restrict__ b_d3,
    float* __restrict__ out)            // [128]
{
    __shared__ float bufA[FUSE_IN];   // activations (input side)
    __shared__ float bufF[HIDDEN];    // fused features (kept for both heads)

    const int b = blockIdx.x;
    const int t = threadIdx.x;

    // ---- load x row into LDS ----
    if (t < IN_DIM) bufA[t] = x[b * IN_DIM + t];
    __syncthreads();

    // ---- h = relu(W_in x + b_in) ----
    {
        float acc = dot_row(W_in + t * IN_DIM, bufA, IN_DIM / 4) + b_in[t];
        __syncthreads();              // all reads of bufA[0:64] done
        bufA[t] = fmaxf(acc, 0.f);
        __syncthreads();
    }

    // ---- 3 collapsed GAT layers: g = relu(W_l g + b_l) ----
    for (int l = 0; l < 3; ++l) {
        const float* Wl = gat_W + (size_t)l * HIDDEN * HIDDEN + (size_t)t * HIDDEN;
        float acc = dot_row(Wl, bufA, HIDDEN / 4) + gat_b[l * HIDDEN + t];
        __syncthreads();              // reads of bufA done before overwrite
        bufA[t] = fmaxf(acc, 0.f);
        __syncthreads();
    }

    // ---- append company embedding: bufA[256:320] = emb[ci] ----
    const int ci = cidx[b];
    if (t < EMB_DIM) bufA[HIDDEN + t] = emb[(size_t)ci * EMB_DIM + t];
    __syncthreads();

    // ---- fused = relu(W_fuse [g; emb] + b_fuse) -> bufF ----
    {
        float acc = dot_row(W_fuse + (size_t)t * FUSE_IN, bufA, FUSE_IN / 4) + b_fuse[t];
        bufF[t] = fmaxf(acc, 0.f);
    }
    __syncthreads();

    // ---------------- price head ----------------
    if (t < 128) {
        float acc = dot_row(W_p1 + t * HIDDEN, bufF, HIDDEN / 4) + b_p1[t];
        bufA[t] = fmaxf(acc, 0.f);    // p1 in bufA[0:128]
    }
    __syncthreads();
    if (t < 64) {
        float acc = dot_row(W_p2 + t * 128, bufA, 128 / 4) + b_p2[t];
        bufA[128 + t] = fmaxf(acc, 0.f);  // p2 in bufA[128:192]
    }
    __syncthreads();
    if (t < 64) {  // wave 0: 64-lane reduce of W_p3 . p2
        float v = W_p3[t] * bufA[128 + t];
        for (int off = 32; off > 0; off >>= 1) v += __shfl_down(v, off);
        if (t == 0) out[b] = v + b_p3[0];
    }
    __syncthreads();

    // ---------------- direction head ----------------
    if (t < 128) {
        float acc = dot_row(W_d1 + t * HIDDEN, bufF, HIDDEN / 4) + b_d1[t];
        bufA[t] = fmaxf(acc, 0.f);
    }
    __syncthreads();
    if (t < 64) {
        float acc = dot_row(W_d2 + t * 128, bufA, 128 / 4) + b_d2[t];
        bufA[128 + t] = fmaxf(acc, 0.f);
    }
    __syncthreads();
    if (t < 64) {
        float v = W_d3[t] * bufA[128 + t];
        for (int off = 32; off > 0; off >>= 1) v += __shfl_down(v, off);
        if (t == 0) {
            float z = v + b_d3[0];
            out[B_ITEMS + b] = 1.0f / (1.0f + expf(-z));
        }
    }
}

extern "C" void kernel_launch(void* const* d_in, const int* in_sizes, int n_in,
                              void* d_out, int out_size, void* d_ws, size_t ws_size,
                              hipStream_t stream) {
    const float* x      = (const float*)d_in[0];
    const int*   cidx   = (const int*)  d_in[1];
    // d_in[2] = edge_index, d_in[3] = edge_attr  -> numerically irrelevant (see proof above)
    const float* W_in   = (const float*)d_in[4];
    const float* b_in   = (const float*)d_in[5];
    const float* gat_W  = (const float*)d_in[6];
    // d_in[7..10] = att_src, att_dst, gat_We, att_edge -> irrelevant
    const float* gat_b  = (const float*)d_in[11];
    const float* emb    = (const float*)d_in[12];
    const float* W_fuse = (const float*)d_in[13];
    const float* b_fuse = (const float*)d_in[14];
    const float* W_p1   = (const float*)d_in[15];
    const float* b_p1   = (const float*)d_in[16];
    const float* W_p2   = (const float*)d_in[17];
    const float* b_p2   = (const float*)d_in[18];
    const float* W_p3   = (const float*)d_in[19];
    const float* b_p3   = (const float*)d_in[20];
    const float* W_d1   = (const float*)d_in[21];
    const float* b_d1   = (const float*)d_in[22];
    const float* W_d2   = (const float*)d_in[23];
    const float* b_d2   = (const float*)d_in[24];
    const float* W_d3   = (const float*)d_in[25];
    const float* b_d3   = (const float*)d_in[26];

    fin_gat_collapsed<<<B_ITEMS, 256, 0, stream>>>(
        x, cidx, W_in, b_in, gat_W, gat_b, emb, W_fuse, b_fuse,
        W_p1, b_p1, W_p2, b_p2, W_p3, b_p3,
        W_d1, b_d1, W_d2, b_d2, W_d3, b_d3,
        (float*)d_out);
}